// Round 7
// baseline (887.985 us; speedup 1.0000x reference)
//
#include <hip/hip_runtime.h>
#include <math.h>

#define TT 512
#define BB 512
#define FF 14
#define H1 32
#define H2 64

__device__ __forceinline__ float rcpf_(float x) { return __builtin_amdgcn_rcpf(x); }
__device__ __forceinline__ float sigmoidf_(float x) {
    return rcpf_(1.0f + __expf(-x));
}
__device__ __forceinline__ float tanhf_(float x) {
    float e = __expf(-2.0f * fabsf(x));
    float t = (1.0f - e) * rcpf_(1.0f + e);
    return copysignf(t, x);
}

// NOTE: parameter names must not collide with .x/.y/.z/.w member tokens.
#define FMA4(vv, ww)                     \
    a0 = fmaf((vv).x, (ww).x, a0);       \
    a1 = fmaf((vv).y, (ww).y, a1);       \
    a2 = fmaf((vv).z, (ww).z, a2);       \
    a3 = fmaf((vv).w, (ww).w, a3);

// One block per batch row, 1024 threads (16 waves), 512 blocks.
// Rounds 1-6 proved the allocator refuses >60 VGPRs/thread (spills and
// refetches weights from L1 at ~3000 cy/step). Fix: shrink per-thread
// weights to fit the default 8-waves/EU budget (64 unified regs):
//   - every thread owns a QUARTER of a layer-2 gate row (24 floats)
//   - threads 0..511 also own a QUARTER of a layer-1 gate row (12 floats)
// Worst thread: 36 weight floats + ~20 temps < 60 regs -> nothing to spill.
// Partial sums are reduced through LDS; state reads are wave-uniform
// broadcasts (q = t>>8 / t>>7 is constant within a wave).
__global__ __launch_bounds__(1024) void lstm3_kernel(
    const float* __restrict__ x,
    const float* __restrict__ Wih1, const float* __restrict__ Whh1,
    const float* __restrict__ bih1, const float* __restrict__ bhh1,
    const float* __restrict__ Wih2, const float* __restrict__ Whh2,
    const float* __restrict__ bih2, const float* __restrict__ bhh2,
    const float* __restrict__ Wfc1, const float* __restrict__ bfc1,
    const float* __restrict__ Wfc2, const float* __restrict__ bfc2,
    const float* __restrict__ Wfc,  const float* __restrict__ bfc,
    float* __restrict__ out)
{
    const int row = blockIdx.x;
    const int t   = threadIdx.x;

    __shared__ __align__(16) float s12[96];     // [h1(32) | h2(64)]
    __shared__ __align__(16) float s1[2][48];   // [x(14)|pad(2)|h1(32)] db
    __shared__ float g1part[512];               // [q*128 + gate]
    __shared__ float g2part[1024];              // [q*256 + gate]
    __shared__ float mlp1[8];
    __shared__ float mlp2[8];

    const int g2 = t & 255;        // layer-2 gate
    const int q2 = t >> 8;         // quarter (0..3) of the 96-dot
    const int g1 = t & 127;        // layer-1 gate (t<512)
    const int q1 = (t >> 7) & 3;   // quarter (0..3) of the 48-dot

    // ---- layer-2 quarter weights: 24 floats ----
    // vec96 = [Wih2 row (32) | Whh2 row (64)], this thread takes [24*q2, 24*q2+24)
    float w2[24];
    #pragma unroll
    for (int k = 0; k < 24; ++k) {
        const int idx = 24 * q2 + k;
        w2[k] = (idx < H1) ? Wih2[g2 * H1 + idx] : Whh2[g2 * H2 + (idx - H1)];
    }
    const float b2r = (q2 == 0) ? (bih2[g2] + bhh2[g2]) : 0.0f;

    // ---- layer-1 quarter weights: 12 floats (threads 0..511) ----
    // vec48 = [Wih1 row (14) | 0,0 | Whh1 row (32)], take [12*q1, 12*q1+12)
    float w1[12];
    float b1r = 0.0f;
    if (t < 512) {
        #pragma unroll
        for (int k = 0; k < 12; ++k) {
            const int idx = 12 * q1 + k;
            w1[k] = (idx < FF) ? Wih1[g1 * FF + idx]
                  : (idx < 16) ? 0.0f
                               : Whh1[g1 * H1 + (idx - 16)];
        }
        b1r = (q1 == 0) ? (bih1[g1] + bhh1[g1]) : 0.0f;
    }

    float c1r  = 0.0f;   // layer-1 cell state, threads 0..31
    float xreg = 0.0f;   // x prefetch, threads 576..589

    // ---- init: zero state; stage x[0]; prefetch x[1] ----
    if (t < 96) s12[t] = 0.0f;
    if (t < 34) { s1[0][14 + t] = 0.0f; s1[1][14 + t] = 0.0f; }  // pad + h1
    if (t >= 576 && t < 576 + FF) {
        const int f = t - 576;
        s1[0][f] = x[(size_t)0 * BB * FF + row * FF + f];
        xreg     = x[(size_t)1 * BB * FF + row * FF + f];
    }
    __syncthreads();

    for (int step = 0; step < TT; ++step) {
        const int sb = step & 1;
        const int nb = sb ^ 1;

        // ===== P1 =====
        // t<512        : layer-1 quarter-dots (broadcast reads of s1[sb])
        // t in [512,576): h2 update of PREVIOUS step (reads g2part)
        // t in [576,590): stage x[step+1] into s1[nb]
        if (t < 512) {
            const float4* sv = ((const float4*)s1[sb]) + q1 * 3;
            float a0 = b1r, a1 = 0.f, a2 = 0.f, a3 = 0.f;
            float4 v;
            v = sv[0]; FMA4(v, *(const float4*)&w1[0]);
            v = sv[1]; FMA4(v, *(const float4*)&w1[4]);
            v = sv[2]; FMA4(v, *(const float4*)&w1[8]);
            g1part[q1 * 128 + g1] = (a0 + a1) + (a2 + a3);
        } else if (t < 576) {
            if (step > 0) {
                const int j = t - 512;
                const float ig = g2part[j]       + g2part[256 + j]
                               + g2part[512 + j] + g2part[768 + j];
                const float gg = g2part[128 + j] + g2part[384 + j]
                               + g2part[640 + j] + g2part[896 + j];
                const float og = g2part[192 + j] + g2part[448 + j]
                               + g2part[704 + j] + g2part[960 + j];
                const float cn = sigmoidf_(ig) * tanhf_(gg);
                s12[32 + j] = sigmoidf_(og) * tanhf_(cn);
            }
        } else if (t < 576 + FF) {
            const int f = t - 576;
            s1[nb][f] = xreg;   // x[step+1]
            const int tn = (step + 2 < TT) ? (step + 2) : (TT - 1);
            xreg = x[(size_t)tn * BB * FF + row * FF + f];
        }
        __syncthreads();

        // ===== P2: h1/c1 update (threads 0..31) =====
        if (t < 32) {
            const float ig = g1part[t]       + g1part[128 + t]
                           + g1part[256 + t] + g1part[384 + t];
            const float fg = g1part[32 + t]  + g1part[160 + t]
                           + g1part[288 + t] + g1part[416 + t];
            const float gg = g1part[64 + t]  + g1part[192 + t]
                           + g1part[320 + t] + g1part[448 + t];
            const float og = g1part[96 + t]  + g1part[224 + t]
                           + g1part[352 + t] + g1part[480 + t];
            const float cn = sigmoidf_(fg) * c1r + sigmoidf_(ig) * tanhf_(gg);
            c1r = cn;
            const float h = sigmoidf_(og) * tanhf_(cn);
            s12[t] = h;             // for P3 this step
            s1[nb][16 + t] = h;     // for P1 next step
        }
        __syncthreads();

        // ===== P3: layer-2 quarter-dots (all 1024 threads) =====
        {
            const float4* sv = ((const float4*)s12) + q2 * 6;
            float a0 = b2r, a1 = 0.f, a2 = 0.f, a3 = 0.f;
            float4 v;
            v = sv[0]; FMA4(v, *(const float4*)&w2[0]);
            v = sv[1]; FMA4(v, *(const float4*)&w2[4]);
            v = sv[2]; FMA4(v, *(const float4*)&w2[8]);
            v = sv[3]; FMA4(v, *(const float4*)&w2[12]);
            v = sv[4]; FMA4(v, *(const float4*)&w2[16]);
            v = sv[5]; FMA4(v, *(const float4*)&w2[20]);
            g2part[q2 * 256 + g2] = (a0 + a1) + (a2 + a3);
        }
        __syncthreads();
    }

    // ---- final h2 update (step TT-1), threads 0..63 ----
    if (t < 64) {
        const float ig = g2part[t]       + g2part[256 + t]
                       + g2part[512 + t] + g2part[768 + t];
        const float gg = g2part[128 + t] + g2part[384 + t]
                       + g2part[640 + t] + g2part[896 + t];
        const float og = g2part[192 + t] + g2part[448 + t]
                       + g2part[704 + t] + g2part[960 + t];
        const float cn = sigmoidf_(ig) * tanhf_(gg);
        s12[32 + t] = sigmoidf_(og) * tanhf_(cn);
    }
    __syncthreads();

    // ---- MLP head ----
    if (t < 8) {
        float a = bfc1[t];
        #pragma unroll
        for (int k = 0; k < H2; ++k)
            a = fmaf(fmaxf(s12[32 + k], 0.0f), Wfc1[t * H2 + k], a);
        mlp1[t] = fmaxf(a, 0.0f);
    }
    __syncthreads();
    if (t < 8) {
        float a = bfc2[t];
        #pragma unroll
        for (int k = 0; k < 8; ++k) a = fmaf(mlp1[k], Wfc2[t * 8 + k], a);
        mlp2[t] = fmaxf(a, 0.0f);
    }
    __syncthreads();
    if (t == 0) {
        float a = bfc[0];
        #pragma unroll
        for (int k = 0; k < 8; ++k) a = fmaf(mlp2[k], Wfc[k], a);
        out[row] = a;
    }
}

extern "C" void kernel_launch(void* const* d_in, const int* in_sizes, int n_in,
                              void* d_out, int out_size, void* d_ws, size_t ws_size,
                              hipStream_t stream) {
    const float* x    = (const float*)d_in[0];
    const float* Wih1 = (const float*)d_in[1];
    const float* Whh1 = (const float*)d_in[2];
    const float* bih1 = (const float*)d_in[3];
    const float* bhh1 = (const float*)d_in[4];
    const float* Wih2 = (const float*)d_in[5];
    const float* Whh2 = (const float*)d_in[6];
    const float* bih2 = (const float*)d_in[7];
    const float* bhh2 = (const float*)d_in[8];
    const float* Wfc1 = (const float*)d_in[9];
    const float* bfc1 = (const float*)d_in[10];
    const float* Wfc2 = (const float*)d_in[11];
    const float* bfc2 = (const float*)d_in[12];
    const float* Wfc  = (const float*)d_in[13];
    const float* bfc  = (const float*)d_in[14];
    float* out = (float*)d_out;

    lstm3_kernel<<<dim3(BB), dim3(1024), 0, stream>>>(
        x, Wih1, Whh1, bih1, bhh1, Wih2, Whh2, bih2, bhh2,
        Wfc1, bfc1, Wfc2, bfc2, Wfc, bfc, out);
}

// Round 9
// 619.165 us; speedup vs baseline: 1.4342x; 1.4342x over previous
//
#include <hip/hip_runtime.h>
#include <math.h>

#define TT 512
#define BB 512
#define FF 14
#define H1 32
#define H2 64

__device__ __forceinline__ float rcpf_(float x) { return __builtin_amdgcn_rcpf(x); }
__device__ __forceinline__ float sigmoidf_(float x) {
    return rcpf_(1.0f + __expf(-x));
}
__device__ __forceinline__ float tanhf_(float x) {
    float e = __expf(-2.0f * fabsf(x));
    float t = (1.0f - e) * rcpf_(1.0f + e);
    return copysignf(t, x);
}

// DPP cross-lane on the VALU pipe (NOT the LDS pipe). dpp_ctrl must be an
// immediate -> template parameter.
// quad_perm[1,0,3,2]=0xB1 (swap adjacent pair), row_shl N = 0x100+N.
template <int CTRL>
__device__ __forceinline__ float dpp_mov(float v) {
    return __int_as_float(__builtin_amdgcn_update_dpp(
        0, __float_as_int(v), CTRL, 0xF, 0xF, true));
}

#define FMA4(vv, ww)                     \
    a0 = fmaf((vv).x, (ww).x, a0);       \
    a1 = fmaf((vv).y, (ww).y, a1);       \
    a2 = fmaf((vv).z, (ww).z, a2);       \
    a3 = fmaf((vv).w, (ww).w, a3);

// One block per batch row, 832 threads (13 waves), 512 blocks (2 blocks/CU).
// Software-pipelined: waves 0..7 compute layer-2 gates of step i-1 while
// waves 8..11 compute layer-1 gates of step i; wave 12 stages x. ONE barrier
// per step (vs 3 before). All gate reductions are DPP (VALU pipe) — LDS only
// broadcasts the state vectors (2-distinct-address b128 reads = conflict-free)
// and takes ~17 owner writes/step. Rounds 6/7 showed the LDS pipe was the
// bottleneck (~380 LDS instrs/step/CU); this drops it to ~280 cheap ones.
// Lane layout (within group): unit u = lane>>3, type ty=(lane>>1)&3,
// half hf=lane&1 -> gate row r = 64*ty+u (L2) / 32*ty+u (L1).
__global__ __launch_bounds__(832) void lstm3_kernel(
    const float* __restrict__ x,
    const float* __restrict__ Wih1, const float* __restrict__ Whh1,
    const float* __restrict__ bih1, const float* __restrict__ bhh1,
    const float* __restrict__ Wih2, const float* __restrict__ Whh2,
    const float* __restrict__ bih2, const float* __restrict__ bhh2,
    const float* __restrict__ Wfc1, const float* __restrict__ bfc1,
    const float* __restrict__ Wfc2, const float* __restrict__ bfc2,
    const float* __restrict__ Wfc,  const float* __restrict__ bfc,
    float* __restrict__ out)
{
    const int row = blockIdx.x;
    const int l   = threadIdx.x;

    // s2cat[p] = [h1(32) | h2(64)]  (layer-2 state, parity-double-buffered)
    // s1cat[p] = [x(14) | pad(2) | h1(32)]  (layer-1 state)
    __shared__ __align__(16) float s2cat[2][96];
    __shared__ __align__(16) float s1cat[2][48];
    __shared__ float mlp1[8];
    __shared__ float mlp2[8];

    // ---------- group/lane decomposition ----------
    // L2 group: l in [0,512): u2=l>>3 (0..63), ty2=(l>>1)&3, hf2=l&1
    // L1 group: l in [512,768): L=l-512: u1=L>>3 (0..31), ty1=(L>>1)&3, hf1=L&1
    // stagers : l in [768,768+FF)
    const int u2  = l >> 3;
    const int ty2 = (l >> 1) & 3;
    const int hf2 = l & 1;
    const int L   = l - 512;
    const int u1  = L >> 3;
    const int ty1 = (L >> 1) & 3;
    const int hf1 = L & 1;

    // ---------- weights ----------
    float4 w2[12];   // L2 lanes: half of [Wih2 row | Whh2 row] (48 floats)
    float  b2r = 0.0f;
    if (l < 512) {
        const int r2 = 64 * ty2 + u2;
        if (hf2 == 0) {
            const float4* p = (const float4*)(Wih2 + r2 * H1);
            #pragma unroll
            for (int k = 0; k < 8; ++k) w2[k] = p[k];
            const float4* q = (const float4*)(Whh2 + r2 * H2);
            #pragma unroll
            for (int k = 0; k < 4; ++k) w2[8 + k] = q[k];
            b2r = bih2[r2] + bhh2[r2];
        } else {
            const float4* q = (const float4*)(Whh2 + r2 * H2);
            #pragma unroll
            for (int k = 0; k < 12; ++k) w2[k] = q[4 + k];
        }
    }

    float4 w1[6];    // L1 lanes: half of [Wih1 row|pad2|Whh1 row] (24 floats)
    float  b1r = 0.0f;
    if (l >= 512 && l < 768) {
        const int r1 = 32 * ty1 + u1;
        if (hf1 == 0) {
            float tmp[16];
            #pragma unroll
            for (int k = 0; k < FF; ++k) tmp[k] = Wih1[r1 * FF + k];
            tmp[14] = 0.0f; tmp[15] = 0.0f;
            w1[0] = make_float4(tmp[0], tmp[1], tmp[2], tmp[3]);
            w1[1] = make_float4(tmp[4], tmp[5], tmp[6], tmp[7]);
            w1[2] = make_float4(tmp[8], tmp[9], tmp[10], tmp[11]);
            w1[3] = make_float4(tmp[12], tmp[13], tmp[14], tmp[15]);
            const float4* q = (const float4*)(Whh1 + r1 * H1);
            w1[4] = q[0];
            w1[5] = q[1];
            b1r = bih1[r1] + bhh1[r1];
        } else {
            const float4* q = (const float4*)(Whh1 + r1 * H1);
            #pragma unroll
            for (int k = 0; k < 6; ++k) w1[k] = q[2 + k];
        }
    }

    float c1r  = 0.0f;   // layer-1 cell state: L1 owner lanes (L&7)==0
    float xreg = 0.0f;   // x prefetch: stager lanes

    // ---------- init ----------
    if (l < 96) { s2cat[0][l] = 0.0f; }              // h1(-1), h2(-1) = 0
    if (l >= 512 && l < 512 + 34) {                  // pad + h1(-1) in s1cat
        s1cat[0][14 + (l - 512)] = 0.0f;
        if (l < 514) s1cat[1][14 + (l - 512)] = 0.0f;
    }
    if (l >= 768 && l < 768 + FF) {
        const int f = l - 768;
        s1cat[0][f] = x[(size_t)0 * BB * FF + row * FF + f];
        xreg        = x[(size_t)1 * BB * FF + row * FF + f];
    }
    __syncthreads();

    // ---------- pipelined time loop: ONE barrier per iteration ----------
    for (int i = 0; i <= TT; ++i) {
        const int rp = (i - 1) & 1;   // parity holding h1(i-1)||h2(i-2)
        const int cp = i & 1;         // parity being filled for step i
        const int np = cp ^ 1;        // parity for step i+1 staging

        if (l < 512) {
            // ===== layer-2 gates + h2 update for step i-1 =====
            if (i > 0) {
                const float4* sv = ((const float4*)s2cat[rp]) + hf2 * 12;
                float a0 = b2r, a1 = 0.f, a2 = 0.f, a3 = 0.f;
                float4 v;
                v = sv[0];  FMA4(v, w2[0]);
                v = sv[1];  FMA4(v, w2[1]);
                v = sv[2];  FMA4(v, w2[2]);
                v = sv[3];  FMA4(v, w2[3]);
                v = sv[4];  FMA4(v, w2[4]);
                v = sv[5];  FMA4(v, w2[5]);
                v = sv[6];  FMA4(v, w2[6]);
                v = sv[7];  FMA4(v, w2[7]);
                v = sv[8];  FMA4(v, w2[8]);
                v = sv[9];  FMA4(v, w2[9]);
                v = sv[10]; FMA4(v, w2[10]);
                v = sv[11]; FMA4(v, w2[11]);
                float g = (a0 + a1) + (a2 + a3);
                g += dpp_mov<0xB1>(g);             // + other half (xor 1)
                const float fg = dpp_mov<0x102>(g);   // from lane +2 (f)
                const float gg = dpp_mov<0x104>(g);   // from lane +4 (g)
                const float og = dpp_mov<0x106>(g);   // from lane +6 (o)
                (void)fg;  // layer-2 cell is always 0 in the reference
                if ((l & 7) == 0) {
                    const float cn = sigmoidf_(g) * tanhf_(gg);
                    s2cat[cp][32 + u2] = sigmoidf_(og) * tanhf_(cn);
                }
            }
        } else if (l < 768) {
            // ===== layer-1 gates + h1/c1 update for step i =====
            if (i < TT) {
                const float4* sv = ((const float4*)s1cat[cp]) + hf1 * 6;
                float a0 = b1r, a1 = 0.f, a2 = 0.f, a3 = 0.f;
                float4 v;
                v = sv[0]; FMA4(v, w1[0]);
                v = sv[1]; FMA4(v, w1[1]);
                v = sv[2]; FMA4(v, w1[2]);
                v = sv[3]; FMA4(v, w1[3]);
                v = sv[4]; FMA4(v, w1[4]);
                v = sv[5]; FMA4(v, w1[5]);
                float g = (a0 + a1) + (a2 + a3);
                g += dpp_mov<0xB1>(g);
                const float fg = dpp_mov<0x102>(g);
                const float gg = dpp_mov<0x104>(g);
                const float og = dpp_mov<0x106>(g);
                if ((L & 7) == 0) {
                    const float cn = sigmoidf_(fg) * c1r + sigmoidf_(g) * tanhf_(gg);
                    c1r = cn;
                    const float h = sigmoidf_(og) * tanhf_(cn);
                    s1cat[np][16 + u1] = h;   // for layer-1 of step i+1
                    s2cat[cp][u1]      = h;   // for layer-2 of step i
                }
            }
        } else if (l < 768 + FF) {
            // ===== stage x(i+1), prefetch x(i+2) =====
            const int f = l - 768;
            s1cat[np][f] = xreg;
            const int tn = (i + 2 < TT) ? (i + 2) : (TT - 1);
            xreg = x[(size_t)tn * BB * FF + row * FF + f];
        }
        __syncthreads();
    }

    // ---------- MLP head (h2(TT-1) is in s2cat[0][32..96)) ----------
    if (l < 8) {
        float a = bfc1[l];
        #pragma unroll
        for (int k = 0; k < H2; ++k)
            a = fmaf(fmaxf(s2cat[0][32 + k], 0.0f), Wfc1[l * H2 + k], a);
        mlp1[l] = fmaxf(a, 0.0f);
    }
    __syncthreads();
    if (l < 8) {
        float a = bfc2[l];
        #pragma unroll
        for (int k = 0; k < 8; ++k) a = fmaf(mlp1[k], Wfc2[l * 8 + k], a);
        mlp2[l] = fmaxf(a, 0.0f);
    }
    __syncthreads();
    if (l == 0) {
        float a = bfc[0];
        #pragma unroll
        for (int k = 0; k < 8; ++k) a = fmaf(mlp2[k], Wfc[k], a);
        out[row] = a;
    }
}

extern "C" void kernel_launch(void* const* d_in, const int* in_sizes, int n_in,
                              void* d_out, int out_size, void* d_ws, size_t ws_size,
                              hipStream_t stream) {
    const float* x    = (const float*)d_in[0];
    const float* Wih1 = (const float*)d_in[1];
    const float* Whh1 = (const float*)d_in[2];
    const float* bih1 = (const float*)d_in[3];
    const float* bhh1 = (const float*)d_in[4];
    const float* Wih2 = (const float*)d_in[5];
    const float* Whh2 = (const float*)d_in[6];
    const float* bih2 = (const float*)d_in[7];
    const float* bhh2 = (const float*)d_in[8];
    const float* Wfc1 = (const float*)d_in[9];
    const float* bfc1 = (const float*)d_in[10];
    const float* Wfc2 = (const float*)d_in[11];
    const float* bfc2 = (const float*)d_in[12];
    const float* Wfc  = (const float*)d_in[13];
    const float* bfc  = (const float*)d_in[14];
    float* out = (float*)d_out;

    lstm3_kernel<<<dim3(BB), dim3(832), 0, stream>>>(
        x, Wih1, Whh1, bih1, bhh1, Wih2, Whh2, bih2, bhh2,
        Wfc1, bfc1, Wfc2, bfc2, Wfc, bfc, out);
}

// Round 10
// 598.365 us; speedup vs baseline: 1.4840x; 1.0348x over previous
//
#include <hip/hip_runtime.h>
#include <math.h>

#define TT 512
#define BB 512
#define FF 14
#define H1 32
#define H2 64

typedef _Float16 h2v __attribute__((ext_vector_type(2)));

__device__ __forceinline__ float rcpf_(float x) { return __builtin_amdgcn_rcpf(x); }
__device__ __forceinline__ float sigmoidf_(float x) {
    return rcpf_(1.0f + __expf(-x));
}
__device__ __forceinline__ float tanhf_(float x) {
    float e = __expf(-2.0f * fabsf(x));
    float t = (1.0f - e) * rcpf_(1.0f + e);
    return copysignf(t, x);
}

// v_dot2_f32_f16: 2 f16 MACs, fp32 accumulate.
__device__ __forceinline__ float fdot2_(h2v a, h2v b, float c) {
#if __has_builtin(__builtin_amdgcn_fdot2)
    return __builtin_amdgcn_fdot2(a, b, c, false);
#else
    return fmaf((float)a.x, (float)b.x, fmaf((float)a.y, (float)b.y, c));
#endif
}
__device__ __forceinline__ h2v bc_(unsigned u) { return __builtin_bit_cast(h2v, u); }
__device__ __forceinline__ h2v pk_(float lo, float hi) {
    h2v r; r.x = (_Float16)lo; r.y = (_Float16)hi; return r;
}

// DPP cross-lane on the VALU pipe. dpp_ctrl must be an immediate.
template <int CTRL>
__device__ __forceinline__ float dpp_mov(float v) {
    return __int_as_float(__builtin_amdgcn_update_dpp(
        0, __float_as_int(v), CTRL, 0xF, 0xF, true));
}

// One block per batch row, 832 threads (13 waves), 512 blocks (2 blocks/CU).
// Pipelined (1 barrier/step): waves 0..7 = layer-2 of step i-1, waves 8..11 =
// layer-1 of step i, wave 12 stages x. Round-9 analysis: the binder is DS-pipe
// INSTRUCTION throughput (~12 cy per ds_read_b128; 244 DS instrs/CU-step ≈
// the whole 2760-cy step). Fix here: state + weights packed f16 pairs ->
// L2 lanes read 6 b128 instead of 12, L1 3 instead of 6, and v_dot2_f32_f16
// halves FMA instructions. fp32 kept for accumulators/activations/c1.
// Lane layout: unit u=lane>>3, type ty=(lane>>1)&3, half hf=lane&1;
// gate row r = 64*ty+u (L2) / 32*ty+u (L1).
__global__ __launch_bounds__(832) void lstm3_kernel(
    const float* __restrict__ x,
    const float* __restrict__ Wih1, const float* __restrict__ Whh1,
    const float* __restrict__ bih1, const float* __restrict__ bhh1,
    const float* __restrict__ Wih2, const float* __restrict__ Whh2,
    const float* __restrict__ bih2, const float* __restrict__ bhh2,
    const float* __restrict__ Wfc1, const float* __restrict__ bfc1,
    const float* __restrict__ Wfc2, const float* __restrict__ bfc2,
    const float* __restrict__ Wfc,  const float* __restrict__ bfc,
    float* __restrict__ out)
{
    const int row = blockIdx.x;
    const int l   = threadIdx.x;

    // Packed f16-pair state (1 dword = 2 values):
    // s2cat[p]: 48 dw = [h1 (16 dw) | h2 (32 dw)]   (layer-2 input state)
    // s1cat[p]: 24 dw = [x (7 dw) | pad (1 dw) | h1 (16 dw)]
    __shared__ __align__(16) unsigned s2cat[2][48];
    __shared__ __align__(16) unsigned s1cat[2][24];
    __shared__ float mlp1[8];
    __shared__ float mlp2[8];

    const int u2  = l >> 3;
    const int ty2 = (l >> 1) & 3;
    const int hf2 = l & 1;
    const int L   = l - 512;
    const int u1  = L >> 3;
    const int ty1 = (L >> 1) & 3;
    const int hf1 = L & 1;

    // ---------- weights -> packed f16 pairs in VGPRs ----------
    h2v  w2[24];   // L2: half of [Wih2 row (32) | Whh2 row (64)] = 48 f16
    float b2r = 0.0f;
    if (l < 512) {
        const int r2 = 64 * ty2 + u2;
        if (hf2 == 0) {
            const float4* p = (const float4*)(Wih2 + r2 * H1);
            #pragma unroll
            for (int k = 0; k < 8; ++k) {
                float4 v = p[k];
                w2[2 * k]     = pk_(v.x, v.y);
                w2[2 * k + 1] = pk_(v.z, v.w);
            }
            const float4* q = (const float4*)(Whh2 + r2 * H2);
            #pragma unroll
            for (int k = 0; k < 4; ++k) {
                float4 v = q[k];
                w2[16 + 2 * k]     = pk_(v.x, v.y);
                w2[16 + 2 * k + 1] = pk_(v.z, v.w);
            }
            b2r = bih2[r2] + bhh2[r2];
        } else {
            const float4* q = (const float4*)(Whh2 + r2 * H2);
            #pragma unroll
            for (int k = 0; k < 12; ++k) {
                float4 v = q[4 + k];
                w2[2 * k]     = pk_(v.x, v.y);
                w2[2 * k + 1] = pk_(v.z, v.w);
            }
        }
    }

    h2v  w1[12];   // L1: half of [Wih1 row (14)|pad(2)|Whh1 row (32)] = 24 f16
    float b1r = 0.0f;
    if (l >= 512 && l < 768) {
        const int r1 = 32 * ty1 + u1;
        if (hf1 == 0) {
            float tmp[16];
            #pragma unroll
            for (int k = 0; k < FF; ++k) tmp[k] = Wih1[r1 * FF + k];
            tmp[14] = 0.0f; tmp[15] = 0.0f;
            #pragma unroll
            for (int j = 0; j < 8; ++j) w1[j] = pk_(tmp[2 * j], tmp[2 * j + 1]);
            const float4* q = (const float4*)(Whh1 + r1 * H1);
            float4 v = q[0];
            w1[8] = pk_(v.x, v.y); w1[9] = pk_(v.z, v.w);
            v = q[1];
            w1[10] = pk_(v.x, v.y); w1[11] = pk_(v.z, v.w);
            b1r = bih1[r1] + bhh1[r1];
        } else {
            const float4* q = (const float4*)(Whh1 + r1 * H1);
            #pragma unroll
            for (int k = 0; k < 6; ++k) {
                float4 v = q[2 + k];
                w1[2 * k]     = pk_(v.x, v.y);
                w1[2 * k + 1] = pk_(v.z, v.w);
            }
        }
    }

    float c1r  = 0.0f;   // layer-1 cell state (fp32): L1 owner lanes (L&7)==0
    float xreg = 0.0f;   // x prefetch: stager lanes

    // ---------- init ----------
    if (l < 48) s2cat[0][l] = 0u;                     // h1(-1), h2(-2) = 0
    if (l >= 512 && L < 17) {                          // pad dw + h1(-1) = 0
        s1cat[0][7 + L] = 0u;
        if (L == 0) s1cat[1][7] = 0u;                  // pad dw, other parity
    }
    if (l >= 768 && l < 768 + FF) {
        const int f = l - 768;
        ((_Float16*)s1cat[0])[f] = (_Float16)x[(size_t)0 * BB * FF + row * FF + f];
        xreg = x[(size_t)1 * BB * FF + row * FF + f];
    }
    __syncthreads();

    // ---------- pipelined time loop: ONE barrier per iteration ----------
    for (int i = 0; i <= TT; ++i) {
        const int rp = (i - 1) & 1;   // parity holding h1(i-1)||h2(i-2)
        const int cp = i & 1;         // parity being filled for step i
        const int np = cp ^ 1;        // parity for step i+1 staging

        if (l < 512) {
            // ===== layer-2 gates + h2 update for step i-1 =====
            if (i > 0) {
                const uint4* sv = ((const uint4*)s2cat[rp]) + hf2 * 6;
                float a0 = b2r, a1 = 0.f, a2 = 0.f, a3 = 0.f;
                #pragma unroll
                for (int k = 0; k < 6; ++k) {
                    uint4 u = sv[k];
                    a0 = fdot2_(w2[4 * k + 0], bc_(u.x), a0);
                    a1 = fdot2_(w2[4 * k + 1], bc_(u.y), a1);
                    a2 = fdot2_(w2[4 * k + 2], bc_(u.z), a2);
                    a3 = fdot2_(w2[4 * k + 3], bc_(u.w), a3);
                }
                float g = (a0 + a1) + (a2 + a3);
                g += dpp_mov<0xB1>(g);                // + other half
                const float gg = dpp_mov<0x104>(g);   // tanh-gate (ty=2)
                const float og = dpp_mov<0x106>(g);   // out-gate  (ty=3)
                if ((l & 7) == 0) {
                    const float cn = sigmoidf_(g) * tanhf_(gg);
                    const float h  = sigmoidf_(og) * tanhf_(cn);
                    ((_Float16*)s2cat[cp])[32 + u2] = (_Float16)h;
                }
            }
        } else if (l < 768) {
            // ===== layer-1 gates + h1/c1 update for step i =====
            if (i < TT) {
                const uint4* sv = ((const uint4*)s1cat[cp]) + hf1 * 3;
                float a0 = b1r, a1 = 0.f, a2 = 0.f, a3 = 0.f;
                #pragma unroll
                for (int k = 0; k < 3; ++k) {
                    uint4 u = sv[k];
                    a0 = fdot2_(w1[4 * k + 0], bc_(u.x), a0);
                    a1 = fdot2_(w1[4 * k + 1], bc_(u.y), a1);
                    a2 = fdot2_(w1[4 * k + 2], bc_(u.z), a2);
                    a3 = fdot2_(w1[4 * k + 3], bc_(u.w), a3);
                }
                float g = (a0 + a1) + (a2 + a3);
                g += dpp_mov<0xB1>(g);
                const float fg = dpp_mov<0x102>(g);
                const float gg = dpp_mov<0x104>(g);
                const float og = dpp_mov<0x106>(g);
                if ((L & 7) == 0) {
                    const float cn = sigmoidf_(fg) * c1r + sigmoidf_(g) * tanhf_(gg);
                    c1r = cn;
                    const float h = sigmoidf_(og) * tanhf_(cn);
                    const _Float16 hh = (_Float16)h;
                    ((_Float16*)s1cat[np])[16 + u1] = hh;  // layer-1, step i+1
                    ((_Float16*)s2cat[cp])[u1]      = hh;  // layer-2, step i
                }
            }
        } else if (l < 768 + FF) {
            // ===== stage x(i+1), prefetch x(i+2) =====
            const int f = l - 768;
            ((_Float16*)s1cat[np])[f] = (_Float16)xreg;
            const int tn = (i + 2 < TT) ? (i + 2) : (TT - 1);
            xreg = x[(size_t)tn * BB * FF + row * FF + f];
        }
        __syncthreads();
    }

    // ---------- MLP head (h2(TT-1) in s2cat[0], f16) ----------
    const _Float16* h2p = (const _Float16*)s2cat[0];
    if (l < 8) {
        float a = bfc1[l];
        #pragma unroll
        for (int k = 0; k < H2; ++k)
            a = fmaf(fmaxf((float)h2p[32 + k], 0.0f), Wfc1[l * H2 + k], a);
        mlp1[l] = fmaxf(a, 0.0f);
    }
    __syncthreads();
    if (l < 8) {
        float a = bfc2[l];
        #pragma unroll
        for (int k = 0; k < 8; ++k) a = fmaf(mlp1[k], Wfc2[l * 8 + k], a);
        mlp2[l] = fmaxf(a, 0.0f);
    }
    __syncthreads();
    if (l == 0) {
        float a = bfc[0];
        #pragma unroll
        for (int k = 0; k < 8; ++k) a = fmaf(mlp2[k], Wfc[k], a);
        out[row] = a;
    }
}

extern "C" void kernel_launch(void* const* d_in, const int* in_sizes, int n_in,
                              void* d_out, int out_size, void* d_ws, size_t ws_size,
                              hipStream_t stream) {
    const float* x    = (const float*)d_in[0];
    const float* Wih1 = (const float*)d_in[1];
    const float* Whh1 = (const float*)d_in[2];
    const float* bih1 = (const float*)d_in[3];
    const float* bhh1 = (const float*)d_in[4];
    const float* Wih2 = (const float*)d_in[5];
    const float* Whh2 = (const float*)d_in[6];
    const float* bih2 = (const float*)d_in[7];
    const float* bhh2 = (const float*)d_in[8];
    const float* Wfc1 = (const float*)d_in[9];
    const float* bfc1 = (const float*)d_in[10];
    const float* Wfc2 = (const float*)d_in[11];
    const float* bfc2 = (const float*)d_in[12];
    const float* Wfc  = (const float*)d_in[13];
    const float* bfc  = (const float*)d_in[14];
    float* out = (float*)d_out;

    lstm3_kernel<<<dim3(BB), dim3(832), 0, stream>>>(
        x, Wih1, Whh1, bih1, bhh1, Wih2, Whh2, bih2, bhh2,
        Wfc1, bfc1, Wfc2, bfc2, Wfc, bfc, out);
}

// Round 12
// 550.853 us; speedup vs baseline: 1.6120x; 1.0863x over previous
//
#include <hip/hip_runtime.h>
#include <math.h>

#define TT 512
#define BB 512
#define FF 14
#define H1 32
#define H2 64

typedef _Float16 h2v __attribute__((ext_vector_type(2)));

__device__ __forceinline__ float rcpf_(float x) { return __builtin_amdgcn_rcpf(x); }
__device__ __forceinline__ float sigmoidf_(float x) {
    return rcpf_(1.0f + __expf(-x));
}
__device__ __forceinline__ float tanhf_(float x) {
    float e = __expf(-2.0f * fabsf(x));
    float t = (1.0f - e) * rcpf_(1.0f + e);
    return copysignf(t, x);
}
__device__ __forceinline__ float fdot2_(h2v a, h2v b, float c) {
#if __has_builtin(__builtin_amdgcn_fdot2)
    return __builtin_amdgcn_fdot2(a, b, c, false);
#else
    return fmaf((float)a.x, (float)b.x, fmaf((float)a.y, (float)b.y, c));
#endif
}
__device__ __forceinline__ h2v bc_(unsigned u) { return __builtin_bit_cast(h2v, u); }
__device__ __forceinline__ h2v pk_(float lo, float hi) {
    h2v r; r.x = (_Float16)lo; r.y = (_Float16)hi; return r;
}
template <int CTRL>
__device__ __forceinline__ float dpp_mov(float v) {
    return __int_as_float(__builtin_amdgcn_update_dpp(
        0, __float_as_int(v), CTRL, 0xF, 0xF, true));
}

// TWO rows per block, 256 blocks = 1 block/CU, 832 threads (13 waves).
// Control flow is round-10's proven structure (dynamic loop, runtime parity
// ints, per-lane role compares); only the [2] row dimension is new. Waves
// 0..7: layer-2 both rows (same weight regs); waves 8..11: layer-1 both rows;
// wave 12: x staging both rows. One barrier/step. Round-10 analysis: step
// time was mostly per-iteration overhead, so double useful work per block.
__global__ __launch_bounds__(832) void lstm3_kernel(
    const float* __restrict__ x,
    const float* __restrict__ Wih1, const float* __restrict__ Whh1,
    const float* __restrict__ bih1, const float* __restrict__ bhh1,
    const float* __restrict__ Wih2, const float* __restrict__ Whh2,
    const float* __restrict__ bih2, const float* __restrict__ bhh2,
    const float* __restrict__ Wfc1, const float* __restrict__ bfc1,
    const float* __restrict__ Wfc2, const float* __restrict__ bfc2,
    const float* __restrict__ Wfc,  const float* __restrict__ bfc,
    float* __restrict__ out)
{
    const int row0 = 2 * blockIdx.x;
    const int l    = threadIdx.x;

    // Packed f16-pair state per [parity][row]:
    // s2cat: 48 dw = [h1 (16 dw) | h2 (32 dw)]
    // s1cat: 24 dw = [x (7 dw) | pad (1 dw) | h1 (16 dw)]
    __shared__ __align__(16) unsigned s2cat[2][2][48];
    __shared__ __align__(16) unsigned s1cat[2][2][24];
    __shared__ float mlp1[2][8];
    __shared__ float mlp2[2][8];

    const int u2  = l >> 3;          // L2 unit (0..63)
    const int hf2 = l & 1;
    const int L   = l - 512;
    const int u1  = L >> 3;          // L1 unit (0..31)
    const int hf1 = L & 1;

    // ---------- weights -> packed f16 pairs in VGPRs (shared by both rows) ----------
    h2v  w2[24];
    float b2r = 0.0f;
    if (l < 512) {
        const int ty2 = (l >> 1) & 3;
        const int r2 = 64 * ty2 + u2;
        if (hf2 == 0) {
            const float4* p = (const float4*)(Wih2 + r2 * H1);
            #pragma unroll
            for (int k = 0; k < 8; ++k) {
                float4 v = p[k];
                w2[2 * k] = pk_(v.x, v.y); w2[2 * k + 1] = pk_(v.z, v.w);
            }
            const float4* q = (const float4*)(Whh2 + r2 * H2);
            #pragma unroll
            for (int k = 0; k < 4; ++k) {
                float4 v = q[k];
                w2[16 + 2 * k] = pk_(v.x, v.y); w2[16 + 2 * k + 1] = pk_(v.z, v.w);
            }
            b2r = bih2[r2] + bhh2[r2];
        } else {
            const float4* q = (const float4*)(Whh2 + r2 * H2);
            #pragma unroll
            for (int k = 0; k < 12; ++k) {
                float4 v = q[4 + k];
                w2[2 * k] = pk_(v.x, v.y); w2[2 * k + 1] = pk_(v.z, v.w);
            }
        }
    }

    h2v  w1[12];
    float b1r = 0.0f;
    if (l >= 512 && l < 768) {
        const int ty1 = (L >> 1) & 3;
        const int r1 = 32 * ty1 + u1;
        if (hf1 == 0) {
            float tmp[16];
            #pragma unroll
            for (int k = 0; k < FF; ++k) tmp[k] = Wih1[r1 * FF + k];
            tmp[14] = 0.0f; tmp[15] = 0.0f;
            #pragma unroll
            for (int j = 0; j < 8; ++j) w1[j] = pk_(tmp[2 * j], tmp[2 * j + 1]);
            const float4* q = (const float4*)(Whh1 + r1 * H1);
            float4 v = q[0];
            w1[8] = pk_(v.x, v.y); w1[9] = pk_(v.z, v.w);
            v = q[1];
            w1[10] = pk_(v.x, v.y); w1[11] = pk_(v.z, v.w);
            b1r = bih1[r1] + bhh1[r1];
        } else {
            const float4* q = (const float4*)(Whh1 + r1 * H1);
            #pragma unroll
            for (int k = 0; k < 6; ++k) {
                float4 v = q[2 + k];
                w1[2 * k] = pk_(v.x, v.y); w1[2 * k + 1] = pk_(v.z, v.w);
            }
        }
    }

    float c1r0 = 0.0f, c1r1 = 0.0f;  // layer-1 cell states (owner lanes)
    float xreg = 0.0f;               // x prefetch (stager lanes)

    // stager mapping (wave 12): lane<14 -> row0; 16<=lane<30 -> row1
    const int slane = l - 768;
    int fidx = -1, frr = 0;
    if (slane >= 0) {
        if (slane < FF) { fidx = slane; frr = 0; }
        else if (slane >= 16 && slane < 16 + FF) { fidx = slane - 16; frr = 1; }
    }

    // ---------- init ----------
    if (l < 96) { const int rr = (l >= 48); s2cat[0][rr][l - 48 * rr] = 0u; }
    if (l >= 96 && l < 96 + 34) {            // pad dw + h1(-1), parity 0
        const int Li = l - 96; const int rr = (Li >= 17);
        s1cat[0][rr][7 + Li - 17 * rr] = 0u;
    }
    if (l == 192) s1cat[1][0][7] = 0u;       // pad dw, parity 1
    if (l == 193) s1cat[1][1][7] = 0u;
    if (fidx >= 0) {
        ((_Float16*)s1cat[0][frr])[fidx] =
            (_Float16)x[((size_t)0 * BB + row0 + frr) * FF + fidx];
        xreg = x[((size_t)1 * BB + row0 + frr) * FF + fidx];
    }
    __syncthreads();

    // ---------- pipelined time loop: ONE barrier per iteration ----------
    for (int i = 0; i <= TT; ++i) {
        const int rp = (i - 1) & 1;   // parity holding h1(i-1)||h2(i-2)
        const int cp = i & 1;         // parity being filled for step i
        const int np = cp ^ 1;        // parity for step i+1 staging

        if (l < 512) {
            // ===== layer-2 gates + h2 update for step i-1, rows 0 and 1 =====
            if (i > 0) {
                #pragma unroll
                for (int rr = 0; rr < 2; ++rr) {
                    const uint4* sv = ((const uint4*)s2cat[rp][rr]) + hf2 * 6;
                    float a0 = b2r, a1 = 0.f, a2 = 0.f, a3 = 0.f;
                    #pragma unroll
                    for (int k = 0; k < 6; ++k) {
                        uint4 u = sv[k];
                        a0 = fdot2_(w2[4 * k + 0], bc_(u.x), a0);
                        a1 = fdot2_(w2[4 * k + 1], bc_(u.y), a1);
                        a2 = fdot2_(w2[4 * k + 2], bc_(u.z), a2);
                        a3 = fdot2_(w2[4 * k + 3], bc_(u.w), a3);
                    }
                    float g = (a0 + a1) + (a2 + a3);
                    g += dpp_mov<0xB1>(g);                // + other half
                    const float gg = dpp_mov<0x104>(g);   // tanh-gate
                    const float og = dpp_mov<0x106>(g);   // out-gate
                    if ((l & 7) == 0) {
                        const float cn = sigmoidf_(g) * tanhf_(gg);
                        ((_Float16*)s2cat[cp][rr])[32 + u2] =
                            (_Float16)(sigmoidf_(og) * tanhf_(cn));
                    }
                }
            }
        } else if (l < 768) {
            // ===== layer-1 gates + h1/c1 update for step i, rows 0 and 1 =====
            if (i < TT) {
                #pragma unroll
                for (int rr = 0; rr < 2; ++rr) {
                    const uint4* sv = ((const uint4*)s1cat[cp][rr]) + hf1 * 3;
                    float a0 = b1r, a1 = 0.f, a2 = 0.f, a3 = 0.f;
                    #pragma unroll
                    for (int k = 0; k < 3; ++k) {
                        uint4 u = sv[k];
                        a0 = fdot2_(w1[4 * k + 0], bc_(u.x), a0);
                        a1 = fdot2_(w1[4 * k + 1], bc_(u.y), a1);
                        a2 = fdot2_(w1[4 * k + 2], bc_(u.z), a2);
                        a3 = fdot2_(w1[4 * k + 3], bc_(u.w), a3);
                    }
                    float g = (a0 + a1) + (a2 + a3);
                    g += dpp_mov<0xB1>(g);
                    const float fg = dpp_mov<0x102>(g);
                    const float gg = dpp_mov<0x104>(g);
                    const float og = dpp_mov<0x106>(g);
                    if ((L & 7) == 0) {
                        float& c1 = rr ? c1r1 : c1r0;
                        const float cn = sigmoidf_(fg) * c1 + sigmoidf_(g) * tanhf_(gg);
                        c1 = cn;
                        const _Float16 hh = (_Float16)(sigmoidf_(og) * tanhf_(cn));
                        ((_Float16*)s1cat[np][rr])[16 + u1] = hh;  // step i+1
                        ((_Float16*)s2cat[cp][rr])[u1]      = hh;  // step i
                    }
                }
            }
        } else {
            // ===== stage x(i+1), prefetch x(i+2), both rows =====
            if (i < TT && fidx >= 0) {
                ((_Float16*)s1cat[np][frr])[fidx] = (_Float16)xreg;
                const int tn = (i + 2 < TT) ? (i + 2) : (TT - 1);
                xreg = x[((size_t)tn * BB + row0 + frr) * FF + fidx];
            }
        }
        __syncthreads();
    }

    // ---------- MLP head, both rows (h2(TT-1) f16 in s2cat[0][rr][32..95]) ----------
    if (l < 16) {
        const int rr = l >> 3, j = l & 7;
        const _Float16* h2p = (const _Float16*)s2cat[0][rr];
        float a = bfc1[j];
        #pragma unroll
        for (int k = 0; k < H2; ++k)
            a = fmaf(fmaxf((float)h2p[32 + k], 0.0f), Wfc1[j * H2 + k], a);
        mlp1[rr][j] = fmaxf(a, 0.0f);
    }
    __syncthreads();
    if (l < 16) {
        const int rr = l >> 3, j = l & 7;
        float a = bfc2[j];
        #pragma unroll
        for (int k = 0; k < 8; ++k) a = fmaf(mlp1[rr][k], Wfc2[j * 8 + k], a);
        mlp2[rr][j] = fmaxf(a, 0.0f);
    }
    __syncthreads();
    if (l < 2) {
        float a = bfc[0];
        #pragma unroll
        for (int k = 0; k < 8; ++k) a = fmaf(mlp2[l][k], Wfc[k], a);
        out[row0 + l] = a;
    }
}

extern "C" void kernel_launch(void* const* d_in, const int* in_sizes, int n_in,
                              void* d_out, int out_size, void* d_ws, size_t ws_size,
                              hipStream_t stream) {
    const float* x    = (const float*)d_in[0];
    const float* Wih1 = (const float*)d_in[1];
    const float* Whh1 = (const float*)d_in[2];
    const float* bih1 = (const float*)d_in[3];
    const float* bhh1 = (const float*)d_in[4];
    const float* Wih2 = (const float*)d_in[5];
    const float* Whh2 = (const float*)d_in[6];
    const float* bih2 = (const float*)d_in[7];
    const float* bhh2 = (const float*)d_in[8];
    const float* Wfc1 = (const float*)d_in[9];
    const float* bfc1 = (const float*)d_in[10];
    const float* Wfc2 = (const float*)d_in[11];
    const float* bfc2 = (const float*)d_in[12];
    const float* Wfc  = (const float*)d_in[13];
    const float* bfc  = (const float*)d_in[14];
    float* out = (float*)d_out;

    lstm3_kernel<<<dim3(BB / 2), dim3(832), 0, stream>>>(
        x, Wih1, Whh1, bih1, bhh1, Wih2, Whh2, bih2, bhh2,
        Wfc1, bfc1, Wfc2, bfc2, Wfc, bfc, out);
}